// Round 1
// baseline (49.096 us; speedup 1.0000x reference)
//
#include <hip/hip_runtime.h>
#include <math.h>

#define BSZ 16
#define NP 4096
#define MAXGT 32
#define CIN 512
#define NCLS 4

// ---------------------------------------------------------------------------
// Main kernel: one thread per proposal. Block = 256 threads = 256 proposals,
// grid = 256 blocks (16 blocks per batch). Computes per-proposal classify/reg
// dot products (weights staged in LDS, broadcast reads), CE terms, IoU
// mask/argmax over 32 GTs, smooth-L1, then a deterministic block tree-reduce
// of 4 partial sums into workspace.
// ---------------------------------------------------------------------------
__global__ __launch_bounds__(256) void oicr_main(
    const float* __restrict__ v,
    const float* __restrict__ gt_boxes,
    const int*   __restrict__ gt_counts,
    const float* __restrict__ rois,
    const float* __restrict__ labels,
    const float* __restrict__ pre_score,
    const float* __restrict__ cls_w,
    const float* __restrict__ cls_b,
    const float* __restrict__ reg_w,
    const float* __restrict__ reg_b,
    float* __restrict__ partials)
{
    __shared__ float w8[8][CIN];        // 16 KB: rows 0..3 = cls_w, 4..7 = reg_w
    __shared__ float s_bias[8];
    __shared__ float g_x0[MAXGT], g_y0[MAXGT], g_x1[MAXGT], g_y1[MAXGT];
    __shared__ float g_area[MAXGT];
    __shared__ int   g_valid[MAXGT];
    __shared__ int   s_label;
    __shared__ float4 red[256];

    const int tid = threadIdx.x;
    const int b   = blockIdx.x >> 4;              // 16 blocks per batch
    const int p   = ((blockIdx.x & 15) << 8) + tid;
    const int row = b * NP + p;

    // --- stage weights into LDS (coalesced) ---
    for (int i = tid; i < 8 * CIN; i += 256) {
        int c = i >> 9, k = i & (CIN - 1);
        w8[c][k] = (c < 4) ? cls_w[c * CIN + k] : reg_w[(c - 4) * CIN + k];
    }
    if (tid < 8) s_bias[tid] = (tid < 4) ? cls_b[tid] : reg_b[tid - 4];
    if (tid < MAXGT) {
        int cnt = gt_counts[b];
        const float* g = gt_boxes + (size_t)(b * MAXGT + tid) * 4;
        float x0 = g[0], y0 = g[1], x1 = g[2], y1 = g[3];
        g_x0[tid] = x0; g_y0[tid] = y0; g_x1[tid] = x1; g_y1[tid] = y1;
        g_area[tid] = (x1 - x0) * (y1 - y0);
        g_valid[tid] = (tid < cnt) ? 1 : 0;
    }
    if (tid == 0) {
        const float* L = labels + b * NCLS;
        int bi = 0; float bv = L[0];
        #pragma unroll
        for (int c = 1; c < NCLS; ++c) { if (L[c] > bv) { bv = L[c]; bi = c; } }
        s_label = bi;
    }
    __syncthreads();

    // --- dot products: acc[0..3] = classify, acc[4..7] = reg ---
    float acc[8];
    #pragma unroll
    for (int c = 0; c < 8; ++c) acc[c] = 0.f;

    const float4* vrow = (const float4*)(v + (size_t)row * CIN);
    #pragma unroll 8
    for (int k4 = 0; k4 < CIN / 4; ++k4) {
        float4 a = vrow[k4];
        const int k = k4 * 4;
        #pragma unroll
        for (int c = 0; c < 8; ++c) {
            float4 wv = *(const float4*)&w8[c][k];   // wave-uniform -> broadcast
            acc[c] += a.x * wv.x + a.y * wv.y + a.z * wv.z + a.w * wv.w;
        }
    }

    const float cls0 = acc[0] + s_bias[0];
    const float cls1 = acc[1] + s_bias[1];
    const float cls2 = acc[2] + s_bias[2];
    const float cls3 = acc[3] + s_bias[3];
    const float reg0 = acc[4] + s_bias[4];
    const float reg1 = acc[5] + s_bias[5];
    const float reg2 = acc[6] + s_bias[6];
    const float reg3 = acc[7] + s_bias[7];

    const int lbl = s_label;

    // --- background CE: logsumexp(classify) - classify[lbl] ---
    float mB = fmaxf(fmaxf(cls0, cls1), fmaxf(cls2, cls3));
    float lseB = mB + logf(expf(cls0 - mB) + expf(cls1 - mB) +
                           expf(cls2 - mB) + expf(cls3 - mB));
    float clsL = (lbl == 0) ? cls0 : (lbl == 1) ? cls1 : (lbl == 2) ? cls2 : cls3;
    float ce_bg = lseB - clsL;

    // --- foreground CE on clipped logits, weighted by pre_score[lbl] ---
    const float lo = 1e-7f, hi = 1.f - 1e-7f;
    float cc0 = fminf(fmaxf(cls0, lo), hi);
    float cc1 = fminf(fmaxf(cls1, lo), hi);
    float cc2 = fminf(fmaxf(cls2, lo), hi);
    float cc3 = fminf(fmaxf(cls3, lo), hi);
    float mF = fmaxf(fmaxf(cc0, cc1), fmaxf(cc2, cc3));
    float lseF = mF + logf(expf(cc0 - mF) + expf(cc1 - mF) +
                           expf(cc2 - mF) + expf(cc3 - mF));
    float ccL = (lbl == 0) ? cc0 : (lbl == 1) ? cc1 : (lbl == 2) ? cc2 : cc3;
    float ce_fg = lseF - ccL;
    float ps = pre_score[(size_t)row * NCLS + lbl];

    // --- IoU over 32 GTs: mask = any(iou > 0.5), idx = first-occurrence argmax ---
    float4 r = *(const float4*)(rois + (size_t)row * 4);
    float rarea = (r.z - r.x) * (r.w - r.y);
    float best = -3.0e38f;
    int   bi = 0;
    int   mk = 0;
    #pragma unroll
    for (int g = 0; g < MAXGT; ++g) {
        float ix0 = fmaxf(r.x, g_x0[g]);
        float iy0 = fmaxf(r.y, g_y0[g]);
        float ix1 = fminf(r.z, g_x1[g]);
        float iy1 = fminf(r.w, g_y1[g]);
        float iw = fmaxf(ix1 - ix0, 0.f);
        float ih = fmaxf(iy1 - iy0, 0.f);
        float inter = iw * ih;
        float iou = inter / (g_area[g] + rarea - inter);
        iou = g_valid[g] ? iou : -1.0f;
        if (iou > best) { best = iou; bi = g; }   // strict > => first max (numpy)
        mk |= (iou > 0.5f) ? 1 : 0;
    }
    float maskf = mk ? 1.f : 0.f;

    // --- bbox regression targets from gt_boxes[bi] ---
    float gx0 = g_x0[bi], gy0 = g_y0[bi], gx1 = g_x1[bi], gy1 = g_y1[bi];
    float gx = (gx1 + gx0) * 0.5f, gy = (gy1 + gy0) * 0.5f;
    float gw = (gx1 - gx0) * 0.5f, gh = (gy1 - gy0) * 0.5f;
    float rx = (r.z + r.x) * 0.5f, ry = (r.w + r.y) * 0.5f;
    float rw = (r.z - r.x) * 0.5f, rh = (r.w - r.y) * 0.5f;
    float tx = (gx - rx) / (rw + 1e-8f);
    float ty = (gy - ry) / (rh + 1e-8f);
    float tw = logf(gw / (rw + 1e-8f));
    float th = logf(gh / (rh + 1e-8f));

    float d0 = reg0 - tx, d1 = reg1 - ty, d2 = reg2 - tw, d3 = reg3 - th;
    float a0 = fabsf(d0), a1 = fabsf(d1), a2 = fabsf(d2), a3 = fabsf(d3);
    float s0 = (a0 < 1.f) ? 0.5f * a0 * a0 : a0 - 0.5f;
    float s1 = (a1 < 1.f) ? 0.5f * a1 * a1 : a1 - 0.5f;
    float s2 = (a2 < 1.f) ? 0.5f * a2 * a2 : a2 - 0.5f;
    float s3 = (a3 < 1.f) ? 0.5f * a3 * a3 : a3 - 0.5f;
    float sl1 = s0 + s1 + s2 + s3;

    float4 part;
    part.x = ce_bg;                    // sum -> ce_bg mean
    part.y = ce_fg * ps * maskf;       // sum -> c_fg numerator
    part.z = maskf;                    // sum -> c_fg denominator
    part.w = sl1 * maskf * ps;         // sum -> l1 numerator

    // --- deterministic block tree-reduce ---
    red[tid] = part;
    __syncthreads();
    #pragma unroll
    for (int s = 128; s > 0; s >>= 1) {
        if (tid < s) {
            float4 o = red[tid + s];
            float4 m2 = red[tid];
            m2.x += o.x; m2.y += o.y; m2.z += o.z; m2.w += o.w;
            red[tid] = m2;
        }
        __syncthreads();
    }
    if (tid == 0) {
        float4 t4 = red[0];
        partials[(size_t)blockIdx.x * 4 + 0] = t4.x;
        partials[(size_t)blockIdx.x * 4 + 1] = t4.y;
        partials[(size_t)blockIdx.x * 4 + 2] = t4.z;
        partials[(size_t)blockIdx.x * 4 + 3] = t4.w;
    }
}

// ---------------------------------------------------------------------------
// Final combine: lanes 0..15 each sum their batch's 16 block-partials in fixed
// order, compute the per-batch terms, then a wave shuffle-reduce and one write.
// ---------------------------------------------------------------------------
__global__ __launch_bounds__(64) void oicr_final(
    const float* __restrict__ partials,
    const int*   __restrict__ gt_counts,
    float* __restrict__ out)
{
    const int lane = threadIdx.x;
    float S0 = 0.f, S1 = 0.f, S2 = 0.f, S3 = 0.f;
    float c_term = 0.f, cbg_term = 0.f, bg_term = 0.f, l1_term = 0.f;
    if (lane < BSZ) {
        for (int blk = 0; blk < 16; ++blk) {
            const float* q = partials + (size_t)(lane * 16 + blk) * 4;
            S0 += q[0]; S1 += q[1]; S2 += q[2]; S3 += q[3];
        }
        bool has = gt_counts[lane] > 0;
        float c_fg       = S1 / (S2 + 1e-7f);
        float ce_bg_mean = S0 / (float)NP;
        float l1b        = S3 / (float)(BSZ * NP);
        c_term   = has ? c_fg : 0.f;
        cbg_term = has ? 0.f : ce_bg_mean;
        bg_term  = has ? 0.f : (float)NP;
        l1_term  = has ? l1b : 0.f;
    }
    #pragma unroll
    for (int off = 32; off > 0; off >>= 1) {
        c_term   += __shfl_down(c_term, off);
        cbg_term += __shfl_down(cbg_term, off);
        bg_term  += __shfl_down(bg_term, off);
        l1_term  += __shfl_down(l1_term, off);
    }
    if (lane == 0) {
        out[0] = (c_term + cbg_term / (bg_term + 1e-7f)) / ((float)BSZ + 1e-7f)
                 + l1_term;
    }
}

extern "C" void kernel_launch(void* const* d_in, const int* in_sizes, int n_in,
                              void* d_out, int out_size, void* d_ws, size_t ws_size,
                              hipStream_t stream)
{
    const float* v         = (const float*)d_in[0];
    const float* gt_boxes  = (const float*)d_in[1];
    const int*   gt_counts = (const int*)  d_in[2];
    const float* rois      = (const float*)d_in[3];
    const float* labels    = (const float*)d_in[4];
    const float* pre_score = (const float*)d_in[5];
    const float* cls_w     = (const float*)d_in[6];
    const float* cls_b     = (const float*)d_in[7];
    const float* reg_w     = (const float*)d_in[8];
    const float* reg_b     = (const float*)d_in[9];
    float* out      = (float*)d_out;
    float* partials = (float*)d_ws;   // 256 blocks * 4 floats = 4 KB

    oicr_main<<<dim3(256), dim3(256), 0, stream>>>(
        v, gt_boxes, gt_counts, rois, labels, pre_score,
        cls_w, cls_b, reg_w, reg_b, partials);
    oicr_final<<<dim3(1), dim3(64), 0, stream>>>(partials, gt_counts, out);
}

// Round 2
// 46.692 us; speedup vs baseline: 1.0515x; 1.0515x over previous
//
#include <hip/hip_runtime.h>
#include <math.h>

#define BSZ 16
#define NP 4096
#define MAXGT 32
#define CIN 512
#define NCLS 4
#define PB 64                     // proposals per block
#define NBLK (BSZ * NP / PB)      // 1024 blocks
#define BPB (NP / PB)             // 64 blocks per batch

// ---------------------------------------------------------------------------
// Main kernel: 4 waves per block, 64 proposals per block. Wave w computes the
// dot-product partial over K-quarter w (128 of 512 floats), giving 16 waves/CU
// (4/SIMD) for latency hiding. Partials combine via padded LDS; wave 0 runs
// the epilogue (CE, IoU mask/argmax, smooth-L1) and a deterministic shuffle
// reduce into 4 block partials.
// ---------------------------------------------------------------------------
__global__ __launch_bounds__(256, 4) void oicr_main(
    const float* __restrict__ v,
    const float* __restrict__ gt_boxes,
    const int*   __restrict__ gt_counts,
    const float* __restrict__ rois,
    const float* __restrict__ labels,
    const float* __restrict__ pre_score,
    const float* __restrict__ cls_w,
    const float* __restrict__ cls_b,
    const float* __restrict__ reg_w,
    const float* __restrict__ reg_b,
    float* __restrict__ partials)
{
    __shared__ float w8[8][CIN];          // 16 KB: 0..3 cls_w, 4..7 reg_w
    __shared__ float red8[4][PB][9];      // 9.2 KB, stride 9 -> conflict-free
    __shared__ float s_bias[8];
    __shared__ float g_x0[MAXGT], g_y0[MAXGT], g_x1[MAXGT], g_y1[MAXGT];
    __shared__ float g_area[MAXGT];
    __shared__ int   g_valid[MAXGT];
    __shared__ int   s_label;

    const int tid  = threadIdx.x;
    const int lane = tid & 63;
    const int wv   = tid >> 6;                    // wave id 0..3
    const int b    = blockIdx.x >> 6;             // batch (64 blocks/batch)
    const int p    = (blockIdx.x & 63) * PB + lane;
    const int row  = b * NP + p;

    // --- stage weights into LDS (coalesced across 256 threads) ---
    #pragma unroll
    for (int i = tid; i < 8 * CIN; i += 256) {
        int c = i >> 9, k = i & (CIN - 1);
        w8[c][k] = (c < 4) ? cls_w[c * CIN + k] : reg_w[(c - 4) * CIN + k];
    }
    if (tid < 8) s_bias[tid] = (tid < 4) ? cls_b[tid] : reg_b[tid - 4];
    if (tid < MAXGT) {
        int cnt = gt_counts[b];
        const float* g = gt_boxes + (size_t)(b * MAXGT + tid) * 4;
        float x0 = g[0], y0 = g[1], x1 = g[2], y1 = g[3];
        g_x0[tid] = x0; g_y0[tid] = y0; g_x1[tid] = x1; g_y1[tid] = y1;
        g_area[tid] = (x1 - x0) * (y1 - y0);
        g_valid[tid] = (tid < cnt) ? 1 : 0;
    }
    if (tid == 0) {
        const float* L = labels + b * NCLS;
        int bi = 0; float bv = L[0];
        #pragma unroll
        for (int c = 1; c < NCLS; ++c) { if (L[c] > bv) { bv = L[c]; bi = c; } }
        s_label = bi;
    }
    __syncthreads();

    // --- dot-product partial over this wave's K-quarter ---
    const int kq = __builtin_amdgcn_readfirstlane(wv);   // wave-uniform
    float acc[8];
    #pragma unroll
    for (int c = 0; c < 8; ++c) acc[c] = 0.f;

    const float4* vrow = (const float4*)(v + (size_t)row * CIN) + kq * 32;
    #pragma unroll 8
    for (int i = 0; i < 32; ++i) {
        float4 a = vrow[i];
        const int k = (kq * 32 + i) * 4;
        #pragma unroll
        for (int c = 0; c < 8; ++c) {
            float4 w4 = *(const float4*)&w8[c][k];   // wave-uniform -> broadcast
            acc[c] += a.x * w4.x + a.y * w4.y + a.z * w4.z + a.w * w4.w;
        }
    }

    #pragma unroll
    for (int c = 0; c < 8; ++c) red8[wv][lane][c] = acc[c];
    __syncthreads();

    if (wv != 0) return;   // no more barriers below

    // --- combine K-quarters (wave 0 only) ---
    #pragma unroll
    for (int c = 0; c < 8; ++c)
        acc[c] = red8[0][lane][c] + red8[1][lane][c] +
                 red8[2][lane][c] + red8[3][lane][c];

    const float cls0 = acc[0] + s_bias[0];
    const float cls1 = acc[1] + s_bias[1];
    const float cls2 = acc[2] + s_bias[2];
    const float cls3 = acc[3] + s_bias[3];
    const float reg0 = acc[4] + s_bias[4];
    const float reg1 = acc[5] + s_bias[5];
    const float reg2 = acc[6] + s_bias[6];
    const float reg3 = acc[7] + s_bias[7];

    const int lbl = s_label;

    // --- background CE ---
    float mB = fmaxf(fmaxf(cls0, cls1), fmaxf(cls2, cls3));
    float lseB = mB + logf(expf(cls0 - mB) + expf(cls1 - mB) +
                           expf(cls2 - mB) + expf(cls3 - mB));
    float clsL = (lbl == 0) ? cls0 : (lbl == 1) ? cls1 : (lbl == 2) ? cls2 : cls3;
    float ce_bg = lseB - clsL;

    // --- foreground CE on clipped logits ---
    const float lo = 1e-7f, hi = 1.f - 1e-7f;
    float cc0 = fminf(fmaxf(cls0, lo), hi);
    float cc1 = fminf(fmaxf(cls1, lo), hi);
    float cc2 = fminf(fmaxf(cls2, lo), hi);
    float cc3 = fminf(fmaxf(cls3, lo), hi);
    float mF = fmaxf(fmaxf(cc0, cc1), fmaxf(cc2, cc3));
    float lseF = mF + logf(expf(cc0 - mF) + expf(cc1 - mF) +
                           expf(cc2 - mF) + expf(cc3 - mF));
    float ccL = (lbl == 0) ? cc0 : (lbl == 1) ? cc1 : (lbl == 2) ? cc2 : cc3;
    float ce_fg = lseF - ccL;
    float ps = pre_score[(size_t)row * NCLS + lbl];

    // --- IoU over 32 GTs: mask + first-occurrence argmax ---
    float4 r = *(const float4*)(rois + (size_t)row * 4);
    float rarea = (r.z - r.x) * (r.w - r.y);
    float best = -3.0e38f;
    int   bi = 0;
    int   mk = 0;
    #pragma unroll
    for (int g = 0; g < MAXGT; ++g) {
        float ix0 = fmaxf(r.x, g_x0[g]);
        float iy0 = fmaxf(r.y, g_y0[g]);
        float ix1 = fminf(r.z, g_x1[g]);
        float iy1 = fminf(r.w, g_y1[g]);
        float iw = fmaxf(ix1 - ix0, 0.f);
        float ih = fmaxf(iy1 - iy0, 0.f);
        float inter = iw * ih;
        float iou = inter / (g_area[g] + rarea - inter);
        iou = g_valid[g] ? iou : -1.0f;
        if (iou > best) { best = iou; bi = g; }   // strict > => first max
        mk |= (iou > 0.5f) ? 1 : 0;
    }
    float maskf = mk ? 1.f : 0.f;

    // --- bbox targets + smooth L1 ---
    float gx0 = g_x0[bi], gy0 = g_y0[bi], gx1 = g_x1[bi], gy1 = g_y1[bi];
    float gx = (gx1 + gx0) * 0.5f, gy = (gy1 + gy0) * 0.5f;
    float gw = (gx1 - gx0) * 0.5f, gh = (gy1 - gy0) * 0.5f;
    float rx = (r.z + r.x) * 0.5f, ry = (r.w + r.y) * 0.5f;
    float rw = (r.z - r.x) * 0.5f, rh = (r.w - r.y) * 0.5f;
    float tx = (gx - rx) / (rw + 1e-8f);
    float ty = (gy - ry) / (rh + 1e-8f);
    float tw = logf(gw / (rw + 1e-8f));
    float th = logf(gh / (rh + 1e-8f));

    float d0 = reg0 - tx, d1 = reg1 - ty, d2 = reg2 - tw, d3 = reg3 - th;
    float a0 = fabsf(d0), a1 = fabsf(d1), a2 = fabsf(d2), a3 = fabsf(d3);
    float s0 = (a0 < 1.f) ? 0.5f * a0 * a0 : a0 - 0.5f;
    float s1 = (a1 < 1.f) ? 0.5f * a1 * a1 : a1 - 0.5f;
    float s2 = (a2 < 1.f) ? 0.5f * a2 * a2 : a2 - 0.5f;
    float s3 = (a3 < 1.f) ? 0.5f * a3 * a3 : a3 - 0.5f;
    float sl1 = s0 + s1 + s2 + s3;

    float px = ce_bg;                 // -> ce_bg mean
    float py = ce_fg * ps * maskf;    // -> c_fg numerator
    float pz = maskf;                 // -> c_fg denominator
    float pw = sl1 * maskf * ps;      // -> l1 numerator

    // --- deterministic 64-lane shuffle reduce ---
    #pragma unroll
    for (int off = 32; off > 0; off >>= 1) {
        px += __shfl_down(px, off);
        py += __shfl_down(py, off);
        pz += __shfl_down(pz, off);
        pw += __shfl_down(pw, off);
    }
    if (lane == 0) {
        partials[(size_t)blockIdx.x * 4 + 0] = px;
        partials[(size_t)blockIdx.x * 4 + 1] = py;
        partials[(size_t)blockIdx.x * 4 + 2] = pz;
        partials[(size_t)blockIdx.x * 4 + 3] = pw;
    }
}

// ---------------------------------------------------------------------------
// Final combine: lanes 0..15 each sum their batch's 64 block-partials in
// fixed order, compute per-batch terms, wave shuffle-reduce, one write.
// ---------------------------------------------------------------------------
__global__ __launch_bounds__(64) void oicr_final(
    const float* __restrict__ partials,
    const int*   __restrict__ gt_counts,
    float* __restrict__ out)
{
    const int lane = threadIdx.x;
    float S0 = 0.f, S1 = 0.f, S2 = 0.f, S3 = 0.f;
    float c_term = 0.f, cbg_term = 0.f, bg_term = 0.f, l1_term = 0.f;
    if (lane < BSZ) {
        for (int blk = 0; blk < BPB; ++blk) {
            const float* q = partials + (size_t)(lane * BPB + blk) * 4;
            S0 += q[0]; S1 += q[1]; S2 += q[2]; S3 += q[3];
        }
        bool has = gt_counts[lane] > 0;
        float c_fg       = S1 / (S2 + 1e-7f);
        float ce_bg_mean = S0 / (float)NP;
        float l1b        = S3 / (float)(BSZ * NP);
        c_term   = has ? c_fg : 0.f;
        cbg_term = has ? 0.f : ce_bg_mean;
        bg_term  = has ? 0.f : (float)NP;
        l1_term  = has ? l1b : 0.f;
    }
    #pragma unroll
    for (int off = 32; off > 0; off >>= 1) {
        c_term   += __shfl_down(c_term, off);
        cbg_term += __shfl_down(cbg_term, off);
        bg_term  += __shfl_down(bg_term, off);
        l1_term  += __shfl_down(l1_term, off);
    }
    if (lane == 0) {
        out[0] = (c_term + cbg_term / (bg_term + 1e-7f)) / ((float)BSZ + 1e-7f)
                 + l1_term;
    }
}

extern "C" void kernel_launch(void* const* d_in, const int* in_sizes, int n_in,
                              void* d_out, int out_size, void* d_ws, size_t ws_size,
                              hipStream_t stream)
{
    const float* v         = (const float*)d_in[0];
    const float* gt_boxes  = (const float*)d_in[1];
    const int*   gt_counts = (const int*)  d_in[2];
    const float* rois      = (const float*)d_in[3];
    const float* labels    = (const float*)d_in[4];
    const float* pre_score = (const float*)d_in[5];
    const float* cls_w     = (const float*)d_in[6];
    const float* cls_b     = (const float*)d_in[7];
    const float* reg_w     = (const float*)d_in[8];
    const float* reg_b     = (const float*)d_in[9];
    float* out      = (float*)d_out;
    float* partials = (float*)d_ws;   // 1024 blocks * 4 floats = 16 KB

    oicr_main<<<dim3(NBLK), dim3(256), 0, stream>>>(
        v, gt_boxes, gt_counts, rois, labels, pre_score,
        cls_w, cls_b, reg_w, reg_b, partials);
    oicr_final<<<dim3(1), dim3(64), 0, stream>>>(partials, gt_counts, out);
}

// Round 3
// 42.679 us; speedup vs baseline: 1.1504x; 1.0940x over previous
//
#include <hip/hip_runtime.h>
#include <math.h>

#define BSZ 16
#define NP 4096
#define MAXGT 32
#define CIN 512
#define NCLS 4
#define RPT 2                      // rows (proposals) per thread
#define PB (64 * RPT)              // proposals per block = 128
#define NBLK (BSZ * NP / PB)       // 512 blocks
#define BPB (NP / PB)              // 32 blocks per batch

// ---------------------------------------------------------------------------
// Main kernel: 4 waves/block, 128 proposals/block (2 per thread). Wave w
// computes dot-product partials over K-quarter w. Weights are read with
// wave-uniform addresses straight from global (scalar K$/L1 path — NO LDS),
// freeing the LDS pipe; LDS is used only for the 8-float K-combine (padded,
// conflict-free) and tiny per-batch metadata. Wave 0 runs the epilogue for
// both rows and a deterministic shuffle reduce into 4 block partials.
// ---------------------------------------------------------------------------
__global__ __launch_bounds__(256, 2) void oicr_main(
    const float* __restrict__ v,
    const float* __restrict__ gt_boxes,
    const int*   __restrict__ gt_counts,
    const float* __restrict__ rois,
    const float* __restrict__ labels,
    const float* __restrict__ pre_score,
    const float* __restrict__ cls_w,
    const float* __restrict__ cls_b,
    const float* __restrict__ reg_w,
    const float* __restrict__ reg_b,
    float* __restrict__ partials)
{
    __shared__ float red8[4][PB][9];      // 18.4 KB, stride 9 -> conflict-free
    __shared__ float s_bias[8];
    __shared__ float g_x0[MAXGT], g_y0[MAXGT], g_x1[MAXGT], g_y1[MAXGT];
    __shared__ float g_area[MAXGT];
    __shared__ int   g_valid[MAXGT];
    __shared__ int   s_label;

    const int tid   = threadIdx.x;
    const int lane  = tid & 63;
    const int wv    = tid >> 6;                   // wave id 0..3 (K-quarter)
    const int b     = blockIdx.x >> 5;            // 32 blocks per batch
    const int pbase = (blockIdx.x & 31) * PB;
    const int row0  = b * NP + pbase + lane;      // this thread's 2 rows
    const int row1  = row0 + 64;

    // --- stage tiny per-batch metadata (consumed only after post-loop barrier)
    if (tid < 8) s_bias[tid] = (tid < 4) ? cls_b[tid] : reg_b[tid - 4];
    if (tid < MAXGT) {
        int cnt = gt_counts[b];
        const float* g = gt_boxes + (size_t)(b * MAXGT + tid) * 4;
        float x0 = g[0], y0 = g[1], x1 = g[2], y1 = g[3];
        g_x0[tid] = x0; g_y0[tid] = y0; g_x1[tid] = x1; g_y1[tid] = y1;
        g_area[tid] = (x1 - x0) * (y1 - y0);
        g_valid[tid] = (tid < cnt) ? 1 : 0;
    }
    if (tid == 0) {
        const float* L = labels + b * NCLS;
        int bi = 0; float bv = L[0];
        #pragma unroll
        for (int c = 1; c < NCLS; ++c) { if (L[c] > bv) { bv = L[c]; bi = c; } }
        s_label = bi;
    }

    // --- dot-product partials over this wave's K-quarter, 2 rows/thread ---
    const int kq = __builtin_amdgcn_readfirstlane(wv);   // wave-uniform
    float acc0[8], acc1[8];
    #pragma unroll
    for (int c = 0; c < 8; ++c) { acc0[c] = 0.f; acc1[c] = 0.f; }

    const float4* vr0 = (const float4*)(v + (size_t)row0 * CIN) + kq * 32;
    const float4* vr1 = (const float4*)(v + (size_t)row1 * CIN) + kq * 32;

    #pragma unroll 8
    for (int i = 0; i < 32; ++i) {
        float4 a0 = vr0[i];
        float4 a1 = vr1[i];
        const int k = (kq * 32 + i) * 4;             // uniform
        #pragma unroll
        for (int c = 0; c < 4; ++c) {
            float4 wc = *(const float4*)&cls_w[c * CIN + k];  // uniform -> s_load
            float4 wr = *(const float4*)&reg_w[c * CIN + k];  // uniform -> s_load
            acc0[c]     += a0.x * wc.x + a0.y * wc.y + a0.z * wc.z + a0.w * wc.w;
            acc1[c]     += a1.x * wc.x + a1.y * wc.y + a1.z * wc.z + a1.w * wc.w;
            acc0[4 + c] += a0.x * wr.x + a0.y * wr.y + a0.z * wr.z + a0.w * wr.w;
            acc1[4 + c] += a1.x * wr.x + a1.y * wr.y + a1.z * wr.z + a1.w * wr.w;
        }
    }

    #pragma unroll
    for (int c = 0; c < 8; ++c) {
        red8[wv][lane][c]      = acc0[c];
        red8[wv][64 + lane][c] = acc1[c];
    }
    __syncthreads();

    if (wv != 0) return;   // no barriers below

    // --- wave 0: combine K-quarters + epilogue for both rows ---
    float px = 0.f, py = 0.f, pz = 0.f, pw = 0.f;

    #pragma unroll
    for (int rr = 0; rr < RPT; ++rr) {
        const int li  = rr * 64 + lane;
        const int row = row0 + rr * 64;

        float acc[8];
        #pragma unroll
        for (int c = 0; c < 8; ++c)
            acc[c] = red8[0][li][c] + red8[1][li][c] +
                     red8[2][li][c] + red8[3][li][c];

        const float cls0 = acc[0] + s_bias[0];
        const float cls1 = acc[1] + s_bias[1];
        const float cls2 = acc[2] + s_bias[2];
        const float cls3 = acc[3] + s_bias[3];
        const float reg0 = acc[4] + s_bias[4];
        const float reg1 = acc[5] + s_bias[5];
        const float reg2 = acc[6] + s_bias[6];
        const float reg3 = acc[7] + s_bias[7];

        const int lbl = s_label;

        // background CE on raw logits
        float mB = fmaxf(fmaxf(cls0, cls1), fmaxf(cls2, cls3));
        float lseB = mB + logf(expf(cls0 - mB) + expf(cls1 - mB) +
                               expf(cls2 - mB) + expf(cls3 - mB));
        float clsL = (lbl == 0) ? cls0 : (lbl == 1) ? cls1 : (lbl == 2) ? cls2 : cls3;
        float ce_bg = lseB - clsL;

        // foreground CE on clipped logits
        const float lo = 1e-7f, hi = 1.f - 1e-7f;
        float cc0 = fminf(fmaxf(cls0, lo), hi);
        float cc1 = fminf(fmaxf(cls1, lo), hi);
        float cc2 = fminf(fmaxf(cls2, lo), hi);
        float cc3 = fminf(fmaxf(cls3, lo), hi);
        float mF = fmaxf(fmaxf(cc0, cc1), fmaxf(cc2, cc3));
        float lseF = mF + logf(expf(cc0 - mF) + expf(cc1 - mF) +
                               expf(cc2 - mF) + expf(cc3 - mF));
        float ccL = (lbl == 0) ? cc0 : (lbl == 1) ? cc1 : (lbl == 2) ? cc2 : cc3;
        float ce_fg = lseF - ccL;
        float ps = pre_score[(size_t)row * NCLS + lbl];

        // IoU over 32 GTs: mask + first-occurrence argmax
        float4 r = *(const float4*)(rois + (size_t)row * 4);
        float rarea = (r.z - r.x) * (r.w - r.y);
        float best = -3.0e38f;
        int   bi = 0;
        int   mk = 0;
        #pragma unroll
        for (int g = 0; g < MAXGT; ++g) {
            float ix0 = fmaxf(r.x, g_x0[g]);
            float iy0 = fmaxf(r.y, g_y0[g]);
            float ix1 = fminf(r.z, g_x1[g]);
            float iy1 = fminf(r.w, g_y1[g]);
            float iw = fmaxf(ix1 - ix0, 0.f);
            float ih = fmaxf(iy1 - iy0, 0.f);
            float inter = iw * ih;
            float iou = inter / (g_area[g] + rarea - inter);
            iou = g_valid[g] ? iou : -1.0f;
            if (iou > best) { best = iou; bi = g; }   // strict > => first max
            mk |= (iou > 0.5f) ? 1 : 0;
        }
        float maskf = mk ? 1.f : 0.f;

        // bbox targets + smooth L1
        float gx0 = g_x0[bi], gy0 = g_y0[bi], gx1 = g_x1[bi], gy1 = g_y1[bi];
        float gx = (gx1 + gx0) * 0.5f, gy = (gy1 + gy0) * 0.5f;
        float gw = (gx1 - gx0) * 0.5f, gh = (gy1 - gy0) * 0.5f;
        float rx = (r.z + r.x) * 0.5f, ry = (r.w + r.y) * 0.5f;
        float rw = (r.z - r.x) * 0.5f, rh = (r.w - r.y) * 0.5f;
        float tx = (gx - rx) / (rw + 1e-8f);
        float ty = (gy - ry) / (rh + 1e-8f);
        float tw = logf(gw / (rw + 1e-8f));
        float th = logf(gh / (rh + 1e-8f));

        float d0 = reg0 - tx, d1 = reg1 - ty, d2 = reg2 - tw, d3 = reg3 - th;
        float a0 = fabsf(d0), a1 = fabsf(d1), a2 = fabsf(d2), a3 = fabsf(d3);
        float s0 = (a0 < 1.f) ? 0.5f * a0 * a0 : a0 - 0.5f;
        float s1 = (a1 < 1.f) ? 0.5f * a1 * a1 : a1 - 0.5f;
        float s2 = (a2 < 1.f) ? 0.5f * a2 * a2 : a2 - 0.5f;
        float s3 = (a3 < 1.f) ? 0.5f * a3 * a3 : a3 - 0.5f;
        float sl1 = s0 + s1 + s2 + s3;

        px += ce_bg;
        py += ce_fg * ps * maskf;
        pz += maskf;
        pw += sl1 * maskf * ps;
    }

    // --- deterministic 64-lane shuffle reduce ---
    #pragma unroll
    for (int off = 32; off > 0; off >>= 1) {
        px += __shfl_down(px, off);
        py += __shfl_down(py, off);
        pz += __shfl_down(pz, off);
        pw += __shfl_down(pw, off);
    }
    if (lane == 0) {
        partials[(size_t)blockIdx.x * 4 + 0] = px;
        partials[(size_t)blockIdx.x * 4 + 1] = py;
        partials[(size_t)blockIdx.x * 4 + 2] = pz;
        partials[(size_t)blockIdx.x * 4 + 3] = pw;
    }
}

// ---------------------------------------------------------------------------
// Final combine: lanes 0..15 each sum their batch's 32 block-partials in
// fixed order, compute per-batch terms, wave shuffle-reduce, one write.
// ---------------------------------------------------------------------------
__global__ __launch_bounds__(64) void oicr_final(
    const float* __restrict__ partials,
    const int*   __restrict__ gt_counts,
    float* __restrict__ out)
{
    const int lane = threadIdx.x;
    float S0 = 0.f, S1 = 0.f, S2 = 0.f, S3 = 0.f;
    float c_term = 0.f, cbg_term = 0.f, bg_term = 0.f, l1_term = 0.f;
    if (lane < BSZ) {
        for (int blk = 0; blk < BPB; ++blk) {
            const float* q = partials + (size_t)(lane * BPB + blk) * 4;
            S0 += q[0]; S1 += q[1]; S2 += q[2]; S3 += q[3];
        }
        bool has = gt_counts[lane] > 0;
        float c_fg       = S1 / (S2 + 1e-7f);
        float ce_bg_mean = S0 / (float)NP;
        float l1b        = S3 / (float)(BSZ * NP);
        c_term   = has ? c_fg : 0.f;
        cbg_term = has ? 0.f : ce_bg_mean;
        bg_term  = has ? 0.f : (float)NP;
        l1_term  = has ? l1b : 0.f;
    }
    #pragma unroll
    for (int off = 32; off > 0; off >>= 1) {
        c_term   += __shfl_down(c_term, off);
        cbg_term += __shfl_down(cbg_term, off);
        bg_term  += __shfl_down(bg_term, off);
        l1_term  += __shfl_down(l1_term, off);
    }
    if (lane == 0) {
        out[0] = (c_term + cbg_term / (bg_term + 1e-7f)) / ((float)BSZ + 1e-7f)
                 + l1_term;
    }
}

extern "C" void kernel_launch(void* const* d_in, const int* in_sizes, int n_in,
                              void* d_out, int out_size, void* d_ws, size_t ws_size,
                              hipStream_t stream)
{
    const float* v         = (const float*)d_in[0];
    const float* gt_boxes  = (const float*)d_in[1];
    const int*   gt_counts = (const int*)  d_in[2];
    const float* rois      = (const float*)d_in[3];
    const float* labels    = (const float*)d_in[4];
    const float* pre_score = (const float*)d_in[5];
    const float* cls_w     = (const float*)d_in[6];
    const float* cls_b     = (const float*)d_in[7];
    const float* reg_w     = (const float*)d_in[8];
    const float* reg_b     = (const float*)d_in[9];
    float* out      = (float*)d_out;
    float* partials = (float*)d_ws;   // 512 blocks * 4 floats = 8 KB

    oicr_main<<<dim3(NBLK), dim3(256), 0, stream>>>(
        v, gt_boxes, gt_counts, rois, labels, pre_score,
        cls_w, cls_b, reg_w, reg_b, partials);
    oicr_final<<<dim3(1), dim3(64), 0, stream>>>(partials, gt_counts, out);
}